// Round 1
// baseline (1110.135 us; speedup 1.0000x reference)
//
#include <hip/hip_runtime.h>

typedef __attribute__((ext_vector_type(4))) float f32x4;
typedef __attribute__((ext_vector_type(8))) short bf16x8;

#define NHEAD 6

__device__ __forceinline__ float bfl(unsigned int u){ union{unsigned int u;float f;}c; c.u=u<<16; return c.f; }
__device__ __forceinline__ float bfh(unsigned int u){ union{unsigned int u;float f;}c; c.u=u&0xFFFF0000u; return c.f; }
__device__ __forceinline__ unsigned short f2bf(float f){
  union{float f;unsigned int u;}c; c.f=f;
  unsigned int x=c.u;
  return (unsigned short)((x + 0x7FFFu + ((x>>16)&1u)) >> 16);
}
__device__ __forceinline__ unsigned int pack2(float a, float b){
  return (unsigned int)f2bf(a) | ((unsigned int)f2bf(b)<<16);
}
__device__ __forceinline__ void unpack8(const uint4 v, float* o){
  o[0]=bfl(v.x); o[1]=bfh(v.x); o[2]=bfl(v.y); o[3]=bfh(v.y);
  o[4]=bfl(v.z); o[5]=bfh(v.z); o[6]=bfl(v.w); o[7]=bfh(v.w);
}

// ---------------- weight cast+transpose: wt[n*K+k] = bf16(w[k*N+n]) ----------------
__global__ void wt_kernel(const float* __restrict__ w, unsigned short* __restrict__ wt,
                          int K, int N){
  int idx = blockIdx.x*256 + threadIdx.x;
  if (idx >= K*N) return;
  int k = idx / N, n = idx - k*N;
  wt[(size_t)n*K + k] = f2bf(w[idx]);
}

// ---------------- LayerNorm (+optional shift+window-partition), f32 in -> bf16 out ----
template<int SHIFT>
__global__ __launch_bounds__(256) void ln_kernel(const float* __restrict__ x,
    const float* __restrict__ gw, const float* __restrict__ bw,
    unsigned short* __restrict__ out){
  int tok  = blockIdx.x*4 + (threadIdx.x>>6);
  int lane = threadIdx.x & 63;
  const float* row = x + (size_t)tok*192;
  float4 v = make_float4(0.f,0.f,0.f,0.f);
  if (lane < 48) v = *(const float4*)(row + lane*4);
  float s  = v.x+v.y+v.z+v.w;
  float s2 = v.x*v.x+v.y*v.y+v.z*v.z+v.w*v.w;
  #pragma unroll
  for (int off=32; off; off>>=1){ s += __shfl_xor(s,off); s2 += __shfl_xor(s2,off); }
  float mu = s*(1.f/192.f);
  float rs = rsqrtf(s2*(1.f/192.f) - mu*mu + 1e-5f);
  size_t otok;
  if (SHIFT){
    int b = tok/3136; int hw = tok - b*3136; int h = hw/56; int w = hw - h*56;
    int hs = h-3; if (hs<0) hs += 56;
    int wsh = w-3; if (wsh<0) wsh += 56;
    int wr = hs/7, r = hs - wr*7, wc = wsh/7, c = wsh - wc*7;
    otok = ((size_t)b*64 + wr*8 + wc)*49 + r*7 + c;
  } else {
    otok = (size_t)tok;
  }
  if (lane < 48){
    int cb = lane*4;
    ushort4 o;
    o.x = f2bf((v.x-mu)*rs*gw[cb+0] + bw[cb+0]);
    o.y = f2bf((v.y-mu)*rs*gw[cb+1] + bw[cb+1]);
    o.z = f2bf((v.z-mu)*rs*gw[cb+2] + bw[cb+2]);
    o.w = f2bf((v.w-mu)*rs*gw[cb+3] + bw[cb+3]);
    *(ushort4*)(out + otok*192 + cb) = o;
  }
}

// ---------------- GEMM: C[M][N] = A[M][K] * BT[N][K]^T + bias, fused epilogues -------
// 128x64 tile, BK=64, 4 waves (2x2), wave tile 64x32 of 16x16x32 bf16 MFMA
enum { EPI_BF16=0, EPI_PROJ=1, EPI_GELU=2, EPI_FINAL=3 };

template<int EPI>
__global__ __launch_bounds__(256) void gemm_kernel(
    const unsigned short* __restrict__ A,
    const unsigned short* __restrict__ BT,
    const float* __restrict__ bias,
    const float* __restrict__ res,
    void* __restrict__ Cout,
    int M, int N, int K)
{
  __shared__ unsigned short lA[128*64];
  __shared__ unsigned short lB[64*64];
  const int tid  = threadIdx.x;
  const int wave = tid>>6, lane = tid&63;
  const int wm = wave>>1, wn = wave&1;
  const int lr = lane&15, lh = lane>>4;
  const int m0 = blockIdx.y*128, n0 = blockIdx.x*64;

  f32x4 zero = {0.f,0.f,0.f,0.f};
  f32x4 acc[4][2];
  #pragma unroll
  for (int i=0;i<4;i++){ acc[i][0]=zero; acc[i][1]=zero; }

  const int row8 = tid>>3, col8 = (tid&7)*8;
  const unsigned short* Ag = A  + (size_t)(m0 + row8)*K + col8;
  const unsigned short* Bg = BT + (size_t)(n0 + row8)*K + col8;

  for (int kt=0; kt<K; kt+=64){
    __syncthreads();
    #pragma unroll
    for (int i=0;i<4;i++){
      __builtin_amdgcn_global_load_lds(
        (const __attribute__((address_space(1))) void*)(Ag + (size_t)i*32*K + kt),
        (__attribute__((address_space(3))) void*)(lA + (i*256 + wave*64)*8),
        16, 0, 0);
    }
    #pragma unroll
    for (int i=0;i<2;i++){
      __builtin_amdgcn_global_load_lds(
        (const __attribute__((address_space(1))) void*)(Bg + (size_t)i*32*K + kt),
        (__attribute__((address_space(3))) void*)(lB + (i*256 + wave*64)*8),
        16, 0, 0);
    }
    __syncthreads();

    bf16x8 af[4][2], bfv[2][2];
    #pragma unroll
    for (int mi=0;mi<4;mi++)
      #pragma unroll
      for (int ks=0;ks<2;ks++)
        af[mi][ks] = *(const bf16x8*)&lA[(wm*64+mi*16+lr)*64 + ks*32 + lh*8];
    #pragma unroll
    for (int ni=0;ni<2;ni++)
      #pragma unroll
      for (int ks=0;ks<2;ks++)
        bfv[ni][ks] = *(const bf16x8*)&lB[(wn*32+ni*16+lr)*64 + ks*32 + lh*8];
    #pragma unroll
    for (int mi=0;mi<4;mi++)
      #pragma unroll
      for (int ni=0;ni<2;ni++)
        #pragma unroll
        for (int ks=0;ks<2;ks++)
          acc[mi][ni] = __builtin_amdgcn_mfma_f32_16x16x32_bf16(
              af[mi][ks], bfv[ni][ks], acc[mi][ni], 0,0,0);
  }

  #pragma unroll
  for (int mi=0;mi<4;mi++){
    #pragma unroll
    for (int ni=0;ni<2;ni++){
      int col = n0 + wn*32 + ni*16 + lr;
      float bv = bias[col];
      #pragma unroll
      for (int r=0;r<4;r++){
        int row = m0 + wm*64 + mi*16 + lh*4 + r;
        float v = acc[mi][ni][r] + bv;
        if (EPI == EPI_BF16){
          ((unsigned short*)Cout)[(size_t)row*N + col] = f2bf(v);
        } else if (EPI == EPI_GELU){
          float g = 0.5f*v*(1.0f + erff(v*0.70710678118654752f));
          ((unsigned short*)Cout)[(size_t)row*N + col] = f2bf(g);
        } else if (EPI == EPI_FINAL){
          size_t idx = (size_t)row*N + col;
          ((float*)Cout)[idx] = res[idx] + v;
        } else { // EPI_PROJ: window-reverse + roll(+3,+3) scatter + residual
          int win = row/49; int nn = row - win*49;
          int b  = win>>6; int wi = win&63; int wr = wi>>3; int wc = wi&7;
          int r7 = nn/7;  int c7 = nn - r7*7;
          int h = wr*7 + r7 + 3; if (h>=56) h-=56;
          int w = wc*7 + c7 + 3; if (w>=56) w-=56;
          size_t idx = (((size_t)b*3136) + h*56 + w)*192 + col;
          ((float*)Cout)[idx] = res[idx] + v;
        }
      }
    }
  }
}

// ---------------- attention: one wave per (window, head); lane = query --------------
__global__ __launch_bounds__(256) void attn_kernel(const unsigned short* __restrict__ qkv,
                                                   unsigned short* __restrict__ aout){
  __shared__ float lds[4][2][49*32];
  const int wave = threadIdx.x>>6, lane = threadIdx.x&63;
  const int unit = blockIdx.x*4 + wave;
  const int win  = unit/NHEAD, head = unit - win*NHEAD;
  const size_t base = (size_t)win*49*576 + head*32;
  float* Kl = lds[wave][0];
  float* Vl = lds[wave][1];

  // stage K, V (bf16 -> f32 LDS)
  #pragma unroll
  for (int i=0;i<4;i++){
    int idx = i*64 + lane;
    if (idx < 196){
      int row = idx>>2, c8 = (idx&3)*8;
      float t[8];
      uint4 kv = *(const uint4*)(qkv + base + 192 + (size_t)row*576 + c8);
      unpack8(kv, t);
      *(float4*)&Kl[row*32+c8]   = make_float4(t[0],t[1],t[2],t[3]);
      *(float4*)&Kl[row*32+c8+4] = make_float4(t[4],t[5],t[6],t[7]);
      uint4 vv = *(const uint4*)(qkv + base + 384 + (size_t)row*576 + c8);
      unpack8(vv, t);
      *(float4*)&Vl[row*32+c8]   = make_float4(t[0],t[1],t[2],t[3]);
      *(float4*)&Vl[row*32+c8+4] = make_float4(t[4],t[5],t[6],t[7]);
    }
  }

  // Q row for this lane (clamped for lanes >= 49) + mask region id
  const int qi = lane < 49 ? lane : 48;
  float q[32];
  {
    const unsigned short* qr = qkv + base + (size_t)qi*576;
    #pragma unroll
    for (int j=0;j<4;j++){
      uint4 t = *(const uint4*)(qr + j*8);
      unpack8(t, &q[j*8]);
    }
  }
  const int wi = win & 63, wr = wi>>3, wc = wi&7;
  const int r7 = qi/7, c7 = qi - r7*7;
  const int rh = (wr<7)?0:((r7<4)?1:2);
  const int rw = (wc<7)?0:((c7<4)?1:2);
  const int id = rh*3 + rw;

  // scores
  float s[49];
  #pragma unroll
  for (int key=0; key<49; key++){
    const float* kr = &Kl[key*32];
    float a = 0.f;
    #pragma unroll
    for (int d=0; d<32; d++) a += q[d]*kr[d];
    int idk = __shfl(id, key);
    s[key] = a*0.17677669529663687f + ((idk==id) ? 0.f : -100.f);
  }
  float m = s[0];
  #pragma unroll
  for (int key=1; key<49; key++) m = fmaxf(m, s[key]);
  float sum = 0.f;
  #pragma unroll
  for (int key=0; key<49; key++){ s[key] = __expf(s[key]-m); sum += s[key]; }

  // O = P V
  float o[32];
  #pragma unroll
  for (int d=0; d<32; d++) o[d] = 0.f;
  #pragma unroll
  for (int key=0; key<49; key++){
    float p = s[key];
    const float* vr = &Vl[key*32];
    #pragma unroll
    for (int d=0; d<32; d++) o[d] += p*vr[d];
  }

  if (lane < 49){
    float inv = 1.f/sum;
    size_t ob = ((size_t)win*49 + lane)*192 + head*32;
    #pragma unroll
    for (int d2=0; d2<16; d2++){
      *(unsigned int*)(aout + ob + d2*2) = pack2(o[2*d2]*inv, o[2*d2+1]*inv);
    }
  }
}

// ---------------- launcher ----------------
extern "C" void kernel_launch(void* const* d_in, const int* in_sizes, int n_in,
                              void* d_out, int out_size, void* d_ws, size_t ws_size,
                              hipStream_t stream){
  (void)in_sizes; (void)n_in; (void)out_size; (void)ws_size;
  const float* x      = (const float*)d_in[0];
  const float* n1_g   = (const float*)d_in[1];
  const float* n1_b   = (const float*)d_in[2];
  const float* qkv_w  = (const float*)d_in[3];
  const float* qkv_b  = (const float*)d_in[4];
  const float* proj_w = (const float*)d_in[5];
  const float* proj_b = (const float*)d_in[6];
  const float* n2_g   = (const float*)d_in[7];
  const float* n2_b   = (const float*)d_in[8];
  const float* w1     = (const float*)d_in[9];
  const float* b1     = (const float*)d_in[10];
  const float* w2     = (const float*)d_in[11];
  const float* b2     = (const float*)d_in[12];

  char* ws = (char*)d_ws;
  unsigned short* qkvT = (unsigned short*)(ws + 0);          // 576*192 bf16
  unsigned short* projT= (unsigned short*)(ws + 221184);     // 192*192
  unsigned short* w1T  = (unsigned short*)(ws + 294912);     // 768*192
  unsigned short* w2T  = (unsigned short*)(ws + 589824);     // 192*768
  unsigned short* bufA = (unsigned short*)(ws + 884736);     // 200704*192 bf16 (xw / attn_out / x2n)
  unsigned short* bufB = (unsigned short*)(ws + 77955072);   // 200704*768 bf16 (qkv / h)
  float*          x2   = (float*)        (ws + 386236416);   // 200704*192 f32
  float* out = (float*)d_out;
  const int M = 200704;

  wt_kernel<<<432,256,0,stream>>>(qkv_w, qkvT, 192, 576);
  wt_kernel<<<144,256,0,stream>>>(proj_w, projT, 192, 192);
  wt_kernel<<<576,256,0,stream>>>(w1,    w1T,  192, 768);
  wt_kernel<<<576,256,0,stream>>>(w2,    w2T,  768, 192);

  ln_kernel<1><<<50176,256,0,stream>>>(x, n1_g, n1_b, bufA);
  gemm_kernel<EPI_BF16 ><<<dim3(9,1568), 256,0,stream>>>(bufA, qkvT, qkv_b, nullptr, bufB, M, 576, 192);
  attn_kernel<<<6144,256,0,stream>>>(bufB, bufA);
  gemm_kernel<EPI_PROJ ><<<dim3(3,1568), 256,0,stream>>>(bufA, projT, proj_b, x, x2, M, 192, 192);
  ln_kernel<0><<<50176,256,0,stream>>>(x2, n2_g, n2_b, bufA);
  gemm_kernel<EPI_GELU ><<<dim3(12,1568),256,0,stream>>>(bufA, w1T, b1, nullptr, bufB, M, 768, 192);
  gemm_kernel<EPI_FINAL><<<dim3(3,1568), 256,0,stream>>>(bufB, w2T, b2, x2, out, M, 192, 768);
}

// Round 2
// 824.377 us; speedup vs baseline: 1.3466x; 1.3466x over previous
//
#include <hip/hip_runtime.h>

typedef __attribute__((ext_vector_type(4))) float f32x4;
typedef __attribute__((ext_vector_type(8))) short bf16x8;

#define NHEAD 6

__device__ __forceinline__ unsigned short f2bf(float f){
  union{float f;unsigned int u;}c; c.f=f;
  unsigned int x=c.u;
  return (unsigned short)((x + 0x7FFFu + ((x>>16)&1u)) >> 16);
}
__device__ __forceinline__ unsigned int pack2(float a, float b){
  return (unsigned int)f2bf(a) | ((unsigned int)f2bf(b)<<16);
}

// ---------------- weight cast+transpose: wt[n*K+k] = bf16(w[k*N+n]) ----------------
__global__ void wt_kernel(const float* __restrict__ w, unsigned short* __restrict__ wt,
                          int K, int N){
  int idx = blockIdx.x*256 + threadIdx.x;
  if (idx >= K*N) return;
  int k = idx / N, n = idx - k*N;
  wt[(size_t)n*K + k] = f2bf(w[idx]);
}

// ---------------- LayerNorm (+optional shift+window-partition), f32 in -> bf16 out ----
template<int SHIFT>
__global__ __launch_bounds__(256) void ln_kernel(const float* __restrict__ x,
    const float* __restrict__ gw, const float* __restrict__ bw,
    unsigned short* __restrict__ out){
  int tok  = blockIdx.x*4 + (threadIdx.x>>6);
  int lane = threadIdx.x & 63;
  const float* row = x + (size_t)tok*192;
  float4 v = make_float4(0.f,0.f,0.f,0.f);
  if (lane < 48) v = *(const float4*)(row + lane*4);
  float s  = v.x+v.y+v.z+v.w;
  float s2 = v.x*v.x+v.y*v.y+v.z*v.z+v.w*v.w;
  #pragma unroll
  for (int off=32; off; off>>=1){ s += __shfl_xor(s,off); s2 += __shfl_xor(s2,off); }
  float mu = s*(1.f/192.f);
  float rs = rsqrtf(s2*(1.f/192.f) - mu*mu + 1e-5f);
  size_t otok;
  if (SHIFT){
    int b = tok/3136; int hw = tok - b*3136; int h = hw/56; int w = hw - h*56;
    int hs = h-3; if (hs<0) hs += 56;
    int wsh = w-3; if (wsh<0) wsh += 56;
    int wr = hs/7, r = hs - wr*7, wc = wsh/7, c = wsh - wc*7;
    otok = ((size_t)b*64 + wr*8 + wc)*49 + r*7 + c;
  } else {
    otok = (size_t)tok;
  }
  if (lane < 48){
    int cb = lane*4;
    ushort4 o;
    o.x = f2bf((v.x-mu)*rs*gw[cb+0] + bw[cb+0]);
    o.y = f2bf((v.y-mu)*rs*gw[cb+1] + bw[cb+1]);
    o.z = f2bf((v.z-mu)*rs*gw[cb+2] + bw[cb+2]);
    o.w = f2bf((v.w-mu)*rs*gw[cb+3] + bw[cb+3]);
    *(ushort4*)(out + otok*192 + cb) = o;
  }
}

// ---------------- GEMM: C[M][N] = A[M][K] * BT[N][K]^T + bias, fused epilogues -------
// 128x64 tile, BK=64, 4 waves (2x2), wave tile 64x32 of 16x16x32 bf16 MFMA
enum { EPI_QKV=0, EPI_PROJ=1, EPI_GELU=2, EPI_FINAL=3 };

template<int EPI>
__global__ __launch_bounds__(256) void gemm_kernel(
    const unsigned short* __restrict__ A,
    const unsigned short* __restrict__ BT,
    const float* __restrict__ bias,
    const float* __restrict__ res,
    void* __restrict__ Cout,
    int M, int N, int K)
{
  __shared__ unsigned short lA[128*64];
  __shared__ unsigned short lB[64*64];
  const int tid  = threadIdx.x;
  const int wave = tid>>6, lane = tid&63;
  const int wm = wave>>1, wn = wave&1;
  const int lr = lane&15, lh = lane>>4;
  const int m0 = blockIdx.y*128, n0 = blockIdx.x*64;

  f32x4 zero = {0.f,0.f,0.f,0.f};
  f32x4 acc[4][2];
  #pragma unroll
  for (int i=0;i<4;i++){ acc[i][0]=zero; acc[i][1]=zero; }

  const int row8 = tid>>3, col8 = (tid&7)*8;
  const unsigned short* Ag = A  + (size_t)(m0 + row8)*K + col8;
  const unsigned short* Bg = BT + (size_t)(n0 + row8)*K + col8;

  for (int kt=0; kt<K; kt+=64){
    __syncthreads();
    #pragma unroll
    for (int i=0;i<4;i++){
      __builtin_amdgcn_global_load_lds(
        (const __attribute__((address_space(1))) void*)(Ag + (size_t)i*32*K + kt),
        (__attribute__((address_space(3))) void*)(lA + (i*256 + wave*64)*8),
        16, 0, 0);
    }
    #pragma unroll
    for (int i=0;i<2;i++){
      __builtin_amdgcn_global_load_lds(
        (const __attribute__((address_space(1))) void*)(Bg + (size_t)i*32*K + kt),
        (__attribute__((address_space(3))) void*)(lB + (i*256 + wave*64)*8),
        16, 0, 0);
    }
    __syncthreads();

    bf16x8 af[4][2], bfv[2][2];
    #pragma unroll
    for (int mi=0;mi<4;mi++)
      #pragma unroll
      for (int ks=0;ks<2;ks++)
        af[mi][ks] = *(const bf16x8*)&lA[(wm*64+mi*16+lr)*64 + ks*32 + lh*8];
    #pragma unroll
    for (int ni=0;ni<2;ni++)
      #pragma unroll
      for (int ks=0;ks<2;ks++)
        bfv[ni][ks] = *(const bf16x8*)&lB[(wn*32+ni*16+lr)*64 + ks*32 + lh*8];
    #pragma unroll
    for (int mi=0;mi<4;mi++)
      #pragma unroll
      for (int ni=0;ni<2;ni++)
        #pragma unroll
        for (int ks=0;ks<2;ks++)
          acc[mi][ni] = __builtin_amdgcn_mfma_f32_16x16x32_bf16(
              af[mi][ks], bfv[ni][ks], acc[mi][ni], 0,0,0);
  }

  #pragma unroll
  for (int mi=0;mi<4;mi++){
    #pragma unroll
    for (int ni=0;ni<2;ni++){
      int col = n0 + wn*32 + ni*16 + lr;
      float bv = bias[col];
      #pragma unroll
      for (int r=0;r<4;r++){
        int row = m0 + wm*64 + mi*16 + lh*4 + r;
        float v = acc[mi][ni][r] + bv;
        if (EPI == EPI_QKV){
          // scatter into [win][which(3)][head(6)][n(49)][d(32)]
          int win = row/49; int n = row - win*49;
          int which = col/192; int rem = col - which*192;
          int head = rem>>5, d = rem&31;
          size_t idx = (size_t)win*28224 + (size_t)which*9408 + head*1568 + n*32 + d;
          ((unsigned short*)Cout)[idx] = f2bf(v);
        } else if (EPI == EPI_GELU){
          float g = 0.5f*v*(1.0f + erff(v*0.70710678118654752f));
          ((unsigned short*)Cout)[(size_t)row*N + col] = f2bf(g);
        } else if (EPI == EPI_FINAL){
          size_t idx = (size_t)row*N + col;
          ((float*)Cout)[idx] = res[idx] + v;
        } else { // EPI_PROJ: window-reverse + roll(+3,+3) scatter + residual
          int win = row/49; int nn = row - win*49;
          int b  = win>>6; int wi = win&63; int wr = wi>>3; int wc = wi&7;
          int r7 = nn/7;  int c7 = nn - r7*7;
          int h = wr*7 + r7 + 3; if (h>=56) h-=56;
          int w = wc*7 + c7 + 3; if (w>=56) w-=56;
          size_t idx = (((size_t)b*3136) + h*56 + w)*192 + col;
          ((float*)Cout)[idx] = res[idx] + v;
        }
      }
    }
  }
}

// ---------------- MFMA attention: one wave per (window, head) ----------------
// qkv layout: [win][which][head][n=49][d=32] bf16 (from EPI_QKV)
// Per wave: Q,K staged to LDS [64][32] (block-XOR swizzled), V^T to [32][64]
// (zeroed cols for key>=49).  S^T = mfma(Kfrag, Qfrag); wave-parallel softmax;
// P (bf16, /sum) to LDS overlay of Q/K; O^T = mfma(Vtfrag, Pfrag).
__global__ __launch_bounds__(256) void attn_kernel(const unsigned short* __restrict__ qkv,
                                                   unsigned short* __restrict__ aout){
  __shared__ __align__(16) unsigned short ldsQK[4][4096]; // per wave: Q[64][32] | K[64][32], reused as P[64][64]
  __shared__ __align__(16) unsigned short ldsV[4][2048];  // per wave: Vt[32][64]
  const int wave = threadIdx.x>>6, lane = threadIdx.x&63;
  const int lr = lane&15, lh = lane>>4;
  const int unit = blockIdx.x*4 + wave;
  const int win  = unit/NHEAD, head = unit - win*NHEAD;

  unsigned short* Q  = ldsQK[wave];
  unsigned short* Kl = ldsQK[wave] + 2048;
  unsigned short* P  = ldsQK[wave];      // overlay (Q/K dead after frag reads)
  unsigned short* Vt = ldsV[wave];

  const size_t wbase = (size_t)win*28224 + (size_t)head*1568;
  const unsigned short* gQ = qkv + wbase;
  const unsigned short* gK = qkv + wbase + 9408;
  const unsigned short* gV = qkv + wbase + 18816;

  // zero Vt (keys 49..63 must be 0.0, not garbage)
  {
    uint4 z = make_uint4(0,0,0,0);
    #pragma unroll
    for (int i=0;i<4;i++) *(uint4*)&Vt[(i*64+lane)*8] = z;
  }

  // stage Q,K: 196 chunks of 8 bf16 each; swizzle block b -> b ^ (row&3) ^ ((row>>2)&3)
  #pragma unroll
  for (int i=0;i<4;i++){
    int idx = i*64 + lane;
    if (idx < 196){
      int row = idx>>2, blk = idx&3;
      int sb = (blk ^ (row&3) ^ ((row>>2)&3));
      uint4 dq = *(const uint4*)(gQ + idx*8);
      *(uint4*)&Q[row*32 + sb*8] = dq;
      uint4 dk = *(const uint4*)(gK + idx*8);
      *(uint4*)&Kl[row*32 + sb*8] = dk;
    }
  }
  // stage V transposed: Vt[d][key], block swizzle b -> b ^ (d&7)
  #pragma unroll
  for (int i=0;i<4;i++){
    int idx = i*64 + lane;
    if (idx < 196){
      int row = idx>>2, d0 = (idx&3)*8;   // key=row, d = d0..d0+7 (d0&7==0)
      uint4 dv = *(const uint4*)(gV + idx*8);
      unsigned int wds[4] = {dv.x, dv.y, dv.z, dv.w};
      int rb = row>>3, re = row&7;
      #pragma unroll
      for (int j=0;j<8;j++){
        unsigned short t = (unsigned short)(wds[j>>1] >> ((j&1)*16));
        Vt[(d0+j)*64 + ((rb ^ j)*8) + re] = t;
      }
    }
  }

  // fragment reads (all before P overwrites Q/K)
  bf16x8 kf[4], qf[4];
  #pragma unroll
  for (int t=0;t<4;t++){
    int row = t*16 + lr;
    int off = row*32 + ((lh ^ (row&3) ^ ((row>>2)&3))*8);
    kf[t] = *(const bf16x8*)&Kl[off];
    qf[t] = *(const bf16x8*)&Q[off];
  }

  // S^T[key][q] : tiles (mi over key, ni over q)
  f32x4 zero = {0.f,0.f,0.f,0.f};
  f32x4 S[4][4];
  #pragma unroll
  for (int mi=0;mi<4;mi++)
    #pragma unroll
    for (int ni=0;ni<4;ni++)
      S[mi][ni] = __builtin_amdgcn_mfma_f32_16x16x32_bf16(kf[mi], qf[ni], zero, 0,0,0);

  // mask / softmax / P store
  const int wi = win & 63, wr = wi>>3, wc = wi&7;
  const bool hasmask = (wr==7) || (wc==7);
  const float scale = 0.17677669529663687f;

  #pragma unroll
  for (int ni=0;ni<4;ni++){
    int q = ni*16 + lr;
    int idq = 0;
    if (hasmask){
      int qr = q/7, qc = q - qr*7;
      int ih = (wr==7) ? ((qr>=4)?2:1) : 0;
      int iw = (wc==7) ? ((qc>=4)?2:1) : 0;
      idq = ih*3 + iw;
    }
    #pragma unroll
    for (int mi=0;mi<4;mi++){
      #pragma unroll
      for (int r=0;r<4;r++){
        int key = mi*16 + lh*4 + r;
        float s;
        if (key >= 49) s = -1e30f;
        else {
          float add = 0.f;
          if (hasmask){
            int kr = key/7, kc = key - kr*7;
            int ih = (wr==7) ? ((kr>=4)?2:1) : 0;
            int iw = (wc==7) ? ((kc>=4)?2:1) : 0;
            add = ((ih*3+iw) == idq) ? 0.f : -100.f;
          }
          s = S[mi][ni][r]*scale + add;
        }
        S[mi][ni][r] = s;
      }
    }
    float m = -1e30f;
    #pragma unroll
    for (int mi=0;mi<4;mi++)
      #pragma unroll
      for (int r=0;r<4;r++) m = fmaxf(m, S[mi][ni][r]);
    m = fmaxf(m, __shfl_xor(m, 16));
    m = fmaxf(m, __shfl_xor(m, 32));
    float sum = 0.f;
    #pragma unroll
    for (int mi=0;mi<4;mi++)
      #pragma unroll
      for (int r=0;r<4;r++){
        float p = __expf(S[mi][ni][r] - m);
        S[mi][ni][r] = p; sum += p;
      }
    sum += __shfl_xor(sum, 16);
    sum += __shfl_xor(sum, 32);
    float inv = 1.f/sum;
    // store P[q][key] bf16, block swizzle b -> b ^ (q&7)
    #pragma unroll
    for (int mi=0;mi<4;mi++){
      int keyb = mi*16 + lh*4;
      int blk = keyb>>3, e0 = keyb&7;
      int addr = q*64 + ((blk ^ (q&7))*8) + e0;
      *(unsigned int*)&P[addr]   = pack2(S[mi][ni][0]*inv, S[mi][ni][1]*inv);
      *(unsigned int*)&P[addr+2] = pack2(S[mi][ni][2]*inv, S[mi][ni][3]*inv);
    }
  }

  // O^T[d][q] = sum_key Vt[d][key] * P[q][key]
  bf16x8 vf[2][2];
  #pragma unroll
  for (int mt=0;mt<2;mt++)
    #pragma unroll
    for (int ks=0;ks<2;ks++){
      int row = mt*16 + lr;
      vf[mt][ks] = *(const bf16x8*)&Vt[row*64 + (((ks*4+lh) ^ (row&7))*8)];
    }
  f32x4 O[2][4];
  #pragma unroll
  for (int ni=0;ni<4;ni++){
    int q = ni*16 + lr;
    bf16x8 pf0 = *(const bf16x8*)&P[q*64 + (((0*4+lh) ^ (q&7))*8)];
    bf16x8 pf1 = *(const bf16x8*)&P[q*64 + (((1*4+lh) ^ (q&7))*8)];
    #pragma unroll
    for (int mt=0;mt<2;mt++){
      f32x4 t = __builtin_amdgcn_mfma_f32_16x16x32_bf16(vf[mt][0], pf0, zero, 0,0,0);
      O[mt][ni] = __builtin_amdgcn_mfma_f32_16x16x32_bf16(vf[mt][1], pf1, t, 0,0,0);
    }
  }

  // write out: lane holds O^T[d = mt*16+lh*4+r][q = ni*16+lr]
  #pragma unroll
  for (int ni=0;ni<4;ni++){
    int q = ni*16 + lr;
    if (q < 49){
      size_t ob = ((size_t)win*49 + q)*192 + head*32 + lh*4;
      #pragma unroll
      for (int mt=0;mt<2;mt++){
        *(unsigned int*)(aout + ob + mt*16)     = pack2(O[mt][ni][0], O[mt][ni][1]);
        *(unsigned int*)(aout + ob + mt*16 + 2) = pack2(O[mt][ni][2], O[mt][ni][3]);
      }
    }
  }
}

// ---------------- launcher ----------------
extern "C" void kernel_launch(void* const* d_in, const int* in_sizes, int n_in,
                              void* d_out, int out_size, void* d_ws, size_t ws_size,
                              hipStream_t stream){
  (void)in_sizes; (void)n_in; (void)out_size; (void)ws_size;
  const float* x      = (const float*)d_in[0];
  const float* n1_g   = (const float*)d_in[1];
  const float* n1_b   = (const float*)d_in[2];
  const float* qkv_w  = (const float*)d_in[3];
  const float* qkv_b  = (const float*)d_in[4];
  const float* proj_w = (const float*)d_in[5];
  const float* proj_b = (const float*)d_in[6];
  const float* n2_g   = (const float*)d_in[7];
  const float* n2_b   = (const float*)d_in[8];
  const float* w1     = (const float*)d_in[9];
  const float* b1     = (const float*)d_in[10];
  const float* w2     = (const float*)d_in[11];
  const float* b2     = (const float*)d_in[12];

  char* ws = (char*)d_ws;
  unsigned short* qkvT = (unsigned short*)(ws + 0);          // 576*192 bf16
  unsigned short* projT= (unsigned short*)(ws + 221184);     // 192*192
  unsigned short* w1T  = (unsigned short*)(ws + 294912);     // 768*192
  unsigned short* w2T  = (unsigned short*)(ws + 589824);     // 192*768
  unsigned short* bufA = (unsigned short*)(ws + 884736);     // 200704*192 bf16 (xw / attn_out / x2n)
  unsigned short* bufB = (unsigned short*)(ws + 77955072);   // 200704*576 bf16 (qkv / h[768])
  float*          x2   = (float*)        (ws + 386236416);   // 200704*192 f32
  float* out = (float*)d_out;
  const int M = 200704;

  wt_kernel<<<432,256,0,stream>>>(qkv_w, qkvT, 192, 576);
  wt_kernel<<<144,256,0,stream>>>(proj_w, projT, 192, 192);
  wt_kernel<<<576,256,0,stream>>>(w1,    w1T,  192, 768);
  wt_kernel<<<576,256,0,stream>>>(w2,    w2T,  768, 192);

  ln_kernel<1><<<50176,256,0,stream>>>(x, n1_g, n1_b, bufA);
  gemm_kernel<EPI_QKV  ><<<dim3(9,1568), 256,0,stream>>>(bufA, qkvT, qkv_b, nullptr, bufB, M, 576, 192);
  attn_kernel<<<6144,256,0,stream>>>(bufB, bufA);
  gemm_kernel<EPI_PROJ ><<<dim3(3,1568), 256,0,stream>>>(bufA, projT, proj_b, x, x2, M, 192, 192);
  ln_kernel<0><<<50176,256,0,stream>>>(x2, n2_g, n2_b, bufA);
  gemm_kernel<EPI_GELU ><<<dim3(12,1568),256,0,stream>>>(bufA, w1T, b1, nullptr, bufB, M, 768, 192);
  gemm_kernel<EPI_FINAL><<<dim3(3,1568), 256,0,stream>>>(bufB, w2T, b2, x2, out, M, 192, 768);
}